// Round 5
// baseline (311.072 us; speedup 1.0000x reference)
//
#include <hip/hip_runtime.h>
#include <math.h>

// Round 5: (1) topic_gru 1024thr, 48-VGPR W slice (survives regalloc heuristic
// that dropped 96-reg slice twice: VGPR=80/88 proved remat), 4 waves/SIMD.
// (2) Fuse 11 dispatches -> 6 (prep{cvt,cvt,gi,kn}, gru, alpha, softmax,
// {hkp+gih}, {slot+score}); gih computes x_in inline. (3) slot BN=128,
// hprev from h16.

#define SEQ 64
#define EMB 128
#define TH 128
#define G3 384
#define KCNT 16384
#define KE 64
#define SH 512
#define GS3 1536
#define INS 513

#define N8H (KCNT * SH / 8)      // 1048576
#define N8W (GS3 * SH / 8)       // 98304
#define NB_CVT_H 2731            // ceil(N8H/384)
#define NB_CVT_W 256             // N8W/384
#define NB_GI 128
#define NB_KN 64
#define GRID_PREP (NB_CVT_H + NB_CVT_W + NB_GI + NB_KN)

#define SLOT_BLOCKS 512          // 128 Mtiles x 4 Ntiles

typedef _Float16 f16x8 __attribute__((ext_vector_type(8)));
typedef float f32x4 __attribute__((ext_vector_type(4)));

__device__ __forceinline__ float sigmoidf_(float x) {
    return 1.0f / (1.0f + expf(-x));
}
__device__ __forceinline__ float sigmoid_fast(float x) {
    return 1.0f / (1.0f + __expf(-x));   // inf-safe
}
__device__ __forceinline__ float tanh_fast(float x) {
    return 2.0f / (1.0f + __expf(-2.0f * x)) - 1.0f;  // inf-safe
}

__device__ __forceinline__ void gl_lds16(const void* g, void* l) {
    __builtin_amdgcn_global_load_lds(
        (const __attribute__((address_space(1))) unsigned int*)g,
        (__attribute__((address_space(3))) unsigned int*)l, 16, 0, 0);
}

// ---------------------------------------------------------------------------
// PREP (one dispatch, 384-thr blocks, block-range demux):
//   [0, 2731)            cvt h0 -> h16
//   [2731, 2987)         cvt Whh_s -> W16
//   [2987, 3115)         topic_gi  (block = (t, dir))
//   [3115, 3179)         kn rows
// ---------------------------------------------------------------------------
__global__ __launch_bounds__(384) void prep_kernel(
    const float* __restrict__ h0, _Float16* __restrict__ h16,
    const float* __restrict__ Whh_s, _Float16* __restrict__ W16,
    const int* __restrict__ topic, const float* __restrict__ emb,
    const float* __restrict__ Wih_f, const float* __restrict__ bih_f,
    const float* __restrict__ Wih_b, const float* __restrict__ bih_b,
    float* __restrict__ gi_ws,
    const float* __restrict__ Wk, const float* __restrict__ bk,
    const float* __restrict__ knowledge, float* __restrict__ kn)
{
    __shared__ float red[8];
    const int b = blockIdx.x;
    const int tid = threadIdx.x;

    if (b < NB_CVT_H + NB_CVT_W) {
        const bool isH = b < NB_CVT_H;
        const float* s = isH ? h0 : Whh_s;
        _Float16* d = isH ? h16 : W16;
        const int n8 = isH ? N8H : N8W;
        const int i = (isH ? b : b - NB_CVT_H) * 384 + tid;
        if (i < n8) {
            const float4* s4 = (const float4*)s + (size_t)i * 2;
            const float4 a = s4[0], c = s4[1];
            f16x8 o;
            o[0] = (_Float16)a.x; o[1] = (_Float16)a.y;
            o[2] = (_Float16)a.z; o[3] = (_Float16)a.w;
            o[4] = (_Float16)c.x; o[5] = (_Float16)c.y;
            o[6] = (_Float16)c.z; o[7] = (_Float16)c.w;
            *(f16x8*)(d + (size_t)i * 8) = o;
        }
        return;
    }
    if (b < NB_CVT_H + NB_CVT_W + NB_GI) {
        const int idx = b - (NB_CVT_H + NB_CVT_W);
        const int t = idx & 63;
        const int dir = idx >> 6;
        const int g = tid;
        const float* Wih = dir ? Wih_b : Wih_f;
        const float* bih = dir ? bih_b : bih_f;
        const int tok = topic[dir ? (SEQ - 1 - t) : t];
        const float4* e4 = (const float4*)(emb + (size_t)tok * EMB);
        const float4* w4 = (const float4*)(Wih + (size_t)g * EMB);
        float acc = bih[g];
        #pragma unroll
        for (int q = 0; q < EMB / 4; ++q) {
            float4 w = w4[q], e = e4[q];
            acc += w.x * e.x + w.y * e.y + w.z * e.z + w.w * e.w;
        }
        gi_ws[((size_t)dir * SEQ + t) * G3 + g] = acc;
        return;
    }
    // kn rows
    {
        const int row = b - (NB_CVT_H + NB_CVT_W + NB_GI);
        const float4* w4 = (const float4*)(Wk + (size_t)row * KCNT);
        const float4* k4 = (const float4*)knowledge;
        float acc = 0.0f;
        for (int i = tid; i < KCNT / 4; i += 384) {
            float4 w = w4[i], k = k4[i];
            acc += w.x * k.x + w.y * k.y + w.z * k.z + w.w * k.w;
        }
        #pragma unroll
        for (int off = 32; off; off >>= 1) acc += __shfl_xor(acc, off);
        if ((tid & 63) == 0) red[tid >> 6] = acc;
        __syncthreads();
        if (tid == 0) {
            float t = bk[row];
            #pragma unroll
            for (int wv = 0; wv < 6; ++wv) t += red[wv];
            kn[row] = t;
        }
    }
}

// ---------------------------------------------------------------------------
// K1: sequential topic GRU. grid 2, 1024 threads.
// thread (j = tid>>3, s = tid&7): output row j, k-slice [s*16, s*16+16).
// W slice = 12 float4 = 48 VGPRs (small enough to stay register-resident).
// gi in LDS (96KB); h double-buffered; 1 barrier/step; xor 1/2/4 reduce.
// ---------------------------------------------------------------------------
__global__ __launch_bounds__(1024) void topic_gru_seq_kernel(
    const float* __restrict__ Whh_f, const float* __restrict__ bhh_f,
    const float* __restrict__ Whh_b, const float* __restrict__ bhh_b,
    const float* __restrict__ gi_ws, float* __restrict__ v_out)
{
    const int dir = blockIdx.x;
    const float* __restrict__ Whh = dir ? Whh_b : Whh_f;
    const float* __restrict__ bhh = dir ? bhh_b : bhh_f;
    const float* __restrict__ gi = gi_ws + (size_t)dir * SEQ * G3;
    const int tid = threadIdx.x;
    const int j = tid >> 3;
    const int s = tid & 7;

    __shared__ float gi_lds[SEQ * G3];   // 96 KB
    __shared__ float hls[2][TH];

    {
        const float4* src = (const float4*)gi;
        float4* dst = (float4*)gi_lds;
        #pragma unroll
        for (int i = 0; i < 6; ++i)
            dst[tid + i * 1024] = src[tid + i * 1024];
    }

    float4 wr[4], wz[4], wn[4];
    {
        const float4* pr = (const float4*)(Whh + (size_t)j * TH + s * 16);
        const float4* pz = (const float4*)(Whh + (size_t)(TH + j) * TH + s * 16);
        const float4* pn = (const float4*)(Whh + (size_t)(2 * TH + j) * TH + s * 16);
        #pragma unroll
        for (int q = 0; q < 4; ++q) { wr[q] = pr[q]; wz[q] = pz[q]; wn[q] = pn[q]; }
    }
    const float bhr = bhh[j], bhz = bhh[j + TH], bhn = bhh[j + 2 * TH];

    if (tid < TH) hls[0][tid] = 0.0f;
    float h_old = 0.0f, vmax = -1e30f;
    __syncthreads();

    int cur = 0;
    for (int t = 0; t < SEQ; ++t) {
        const float4* h4 = (const float4*)(&hls[cur][s * 16]);
        float ar0 = 0.f, ar1 = 0.f, az0 = 0.f, az1 = 0.f, an0 = 0.f, an1 = 0.f;
        #pragma unroll
        for (int q = 0; q < 4; q += 2) {
            const float4 h0v = h4[q], h1v = h4[q + 1];
            ar0 = fmaf(wr[q].x, h0v.x, ar0); ar0 = fmaf(wr[q].y, h0v.y, ar0);
            ar0 = fmaf(wr[q].z, h0v.z, ar0); ar0 = fmaf(wr[q].w, h0v.w, ar0);
            ar1 = fmaf(wr[q+1].x, h1v.x, ar1); ar1 = fmaf(wr[q+1].y, h1v.y, ar1);
            ar1 = fmaf(wr[q+1].z, h1v.z, ar1); ar1 = fmaf(wr[q+1].w, h1v.w, ar1);
            az0 = fmaf(wz[q].x, h0v.x, az0); az0 = fmaf(wz[q].y, h0v.y, az0);
            az0 = fmaf(wz[q].z, h0v.z, az0); az0 = fmaf(wz[q].w, h0v.w, az0);
            az1 = fmaf(wz[q+1].x, h1v.x, az1); az1 = fmaf(wz[q+1].y, h1v.y, az1);
            az1 = fmaf(wz[q+1].z, h1v.z, az1); az1 = fmaf(wz[q+1].w, h1v.w, az1);
            an0 = fmaf(wn[q].x, h0v.x, an0); an0 = fmaf(wn[q].y, h0v.y, an0);
            an0 = fmaf(wn[q].z, h0v.z, an0); an0 = fmaf(wn[q].w, h0v.w, an0);
            an1 = fmaf(wn[q+1].x, h1v.x, an1); an1 = fmaf(wn[q+1].y, h1v.y, an1);
            an1 = fmaf(wn[q+1].z, h1v.z, an1); an1 = fmaf(wn[q+1].w, h1v.w, an1);
        }
        float ar = ar0 + ar1, az = az0 + az1, an = an0 + an1;
        ar += __shfl_xor(ar, 1); ar += __shfl_xor(ar, 2); ar += __shfl_xor(ar, 4);
        az += __shfl_xor(az, 1); az += __shfl_xor(az, 2); az += __shfl_xor(az, 4);
        an += __shfl_xor(an, 1); an += __shfl_xor(an, 2); an += __shfl_xor(an, 4);
        if (s == 0) {
            const float gir = gi_lds[t * G3 + j];
            const float giz = gi_lds[t * G3 + j + TH];
            const float gin = gi_lds[t * G3 + j + 2 * TH];
            const float r = sigmoidf_(gir + ar + bhr);
            const float z = sigmoidf_(giz + az + bhz);
            const float n = tanhf(fmaf(r, an + bhn, gin));
            const float hn = (1.0f - z) * n + z * h_old;
            hls[cur ^ 1][j] = hn;
            h_old = hn;
            vmax = fmaxf(vmax, hn);
        }
        __syncthreads();
        cur ^= 1;
    }
    if (s == 0) v_out[dir * TH + j] = vmax;
}

// ---------------------------------------------------------------------------
// K3: alpha[row] = dot(km[row,:64], kn)
// ---------------------------------------------------------------------------
__global__ __launch_bounds__(256) void alpha_kernel(
    const float* __restrict__ km, const float* __restrict__ kn,
    float* __restrict__ alpha)
{
    const int idx = blockIdx.x * 256 + threadIdx.x;
    const int row = idx >> 6;
    const int lane = idx & 63;
    float p = km[(size_t)row * KE + lane] * kn[lane];
    #pragma unroll
    for (int off = 32; off; off >>= 1) p += __shfl_xor(p, off);
    if (lane == 0) alpha[row] = p;
}

// ---------------------------------------------------------------------------
// K4: beta = softmax(alpha) over 16384
// ---------------------------------------------------------------------------
__global__ __launch_bounds__(1024) void softmax_kernel(
    const float* __restrict__ alpha, float* __restrict__ beta)
{
    const int tid = threadIdx.x;
    float vals[16];
    float m = -1e30f;
    #pragma unroll
    for (int i = 0; i < 16; ++i) {
        vals[i] = alpha[tid + i * 1024];
        m = fmaxf(m, vals[i]);
    }
    #pragma unroll
    for (int off = 32; off; off >>= 1) m = fmaxf(m, __shfl_xor(m, off));
    __shared__ float red[16];
    if ((tid & 63) == 0) red[tid >> 6] = m;
    __syncthreads();
    float M = red[0];
    #pragma unroll
    for (int wv = 1; wv < 16; ++wv) M = fmaxf(M, red[wv]);
    __syncthreads();
    float s = 0.0f;
    #pragma unroll
    for (int i = 0; i < 16; ++i) {
        vals[i] = expf(vals[i] - M);
        s += vals[i];
    }
    #pragma unroll
    for (int off = 32; off; off >>= 1) s += __shfl_xor(s, off);
    if ((tid & 63) == 0) red[tid >> 6] = s;
    __syncthreads();
    float S = 0.0f;
    #pragma unroll
    for (int wv = 0; wv < 16; ++wv) S += red[wv];
    const float inv = 1.0f / S;
    #pragma unroll
    for (int i = 0; i < 16; ++i) beta[tid + i * 1024] = vals[i] * inv;
}

// ---------------------------------------------------------------------------
// K5+K7 fused (512 thr): blocks [0,128) = hkp partials (fp16 h);
// blocks [128, 320) = gih rows (x_in computed inline from v/score).
// ---------------------------------------------------------------------------
__global__ __launch_bounds__(512) void hkp_gih_kernel(
    const float* __restrict__ beta, const _Float16* __restrict__ h16,
    float* __restrict__ part,
    const float* __restrict__ Wih_s, const float* __restrict__ v,
    const float* __restrict__ score, float* __restrict__ g_raw)
{
    const int b = blockIdx.x;
    const int tid = threadIdx.x;
    if (b < 128) {
        const int j = tid;
        const int r0 = b * (KCNT / 128);
        float acc = 0.0f;
        for (int r = 0; r < KCNT / 128; ++r)
            acc = fmaf(beta[r0 + r], (float)h16[(size_t)(r0 + r) * SH + j], acc);
        part[(size_t)b * SH + j] = acc;
        return;
    }
    // gih: 8 rows per block, one wave per row
    const int gid = b - 128;
    const int row = gid * 8 + (tid >> 6);
    const int lane = tid & 63;
    const float sc = score[0];
    const float pos = (sc >= 0.5f) ? 1.0f : 0.0f;
    const float om = 1.0f - pos;
    const float* wrow = Wih_s + (size_t)row * INS;
    float acc = 0.0f;
    for (int k = lane; k < INS; k += 64) {
        const float xv = (k < 256) ? v[k] * pos
                       : (k < 512) ? v[k - 256] * om : sc;
        acc = fmaf(wrow[k], xv, acc);
    }
    #pragma unroll
    for (int off = 32; off; off >>= 1) acc += __shfl_xor(acc, off);
    if (lane == 0) g_raw[row] = acc;
}

// ---------------------------------------------------------------------------
// K8-MFMA + score (513 blocks, 512 thr):
// blocks [0,512): gh = h @ Whh.T fp16 MFMA, fused GRU epilogue.
//   tile 128 rows x 128 cols x 3 gates, BK=32, 8 waves (2m x 4n).
// block 512: predict_score -> out[0] (reduce hkp parts + dot).
// ---------------------------------------------------------------------------
__global__ __launch_bounds__(512, 1) void slot_gru_mfma_kernel(
    const _Float16* __restrict__ h16, // [16384,512]
    const _Float16* __restrict__ W16, // [1536,512]
    const float* __restrict__ beta,   // [16384]
    const float* __restrict__ g_raw,  // [1536]
    const float* __restrict__ b_ih,   // [1536]
    const float* __restrict__ b_hh,   // [1536]
    const float* __restrict__ part,   // [128,512]
    const float* __restrict__ v,      // [256]
    const float* __restrict__ Ws, const float* __restrict__ bs,
    float* __restrict__ out)          // out[0]=score, out+1 = h_new
{
    __shared__ _Float16 As[128 * 32];      // [row][k]   8 KB
    __shared__ _Float16 Bs[384 * 32];      // [g*128+col][k]  24 KB

    const int tid = threadIdx.x;

    if (blockIdx.x == SLOT_BLOCKS) {       // score block
        float* red = (float*)As;
        float hkp = 0.0f;
        for (int b = 0; b < 128; ++b) hkp += part[(size_t)b * SH + tid];
        float contrib = hkp * Ws[256 + tid];
        if (tid < 256) contrib += v[tid] * Ws[tid];
        #pragma unroll
        for (int off = 32; off; off >>= 1) contrib += __shfl_xor(contrib, off);
        if ((tid & 63) == 0) red[tid >> 6] = contrib;
        __syncthreads();
        if (tid == 0) {
            float p = bs[0];
            #pragma unroll
            for (int wv = 0; wv < 8; ++wv) p += red[wv];
            out[0] = p;
        }
        return;
    }

    const int lane = tid & 63;
    const int wv  = tid >> 6;
    const int wm  = (wv >> 2) * 64;
    const int wn  = (wv & 3) * 32;
    const int nt  = blockIdx.x & 3;
    const int mt  = blockIdx.x >> 2;
    const int m0  = mt * 128;
    const int c0  = nt * 128;
    const int l15 = lane & 15;
    const int l4  = lane >> 4;

    f32x4 acc[4][3][2];
    #pragma unroll
    for (int mi = 0; mi < 4; ++mi)
        #pragma unroll
        for (int g = 0; g < 3; ++g)
            #pragma unroll
            for (int ni = 0; ni < 2; ++ni)
                acc[mi][g][ni] = (f32x4){0.f, 0.f, 0.f, 0.f};

    for (int k0 = 0; k0 < SH; k0 += 32) {
        {   // A: 128 rows x 32 k = 512 16B chunks, 1/thread
            const int r = tid >> 2, c = tid & 3;
            gl_lds16(h16 + (size_t)(m0 + r) * SH + k0 + c * 8, &As[tid * 8]);
        }
        #pragma unroll
        for (int p = 0; p < 3; ++p) {   // B: 384 rows x 32 k = 1536 chunks
            const int idx = tid + p * 512;
            const int r = idx >> 2, c = idx & 3;
            const int g = r >> 7, wcol = r & 127;
            gl_lds16(W16 + (size_t)(g * SH + c0 + wcol) * SH + k0 + c * 8,
                     &Bs[idx * 8]);
        }
        __syncthreads();

        f16x8 af[4], bf[3][2];
        #pragma unroll
        for (int mi = 0; mi < 4; ++mi)
            af[mi] = *(const f16x8*)&As[(wm + mi * 16 + l15) * 32 + l4 * 8];
        #pragma unroll
        for (int g = 0; g < 3; ++g)
            #pragma unroll
            for (int ni = 0; ni < 2; ++ni)
                bf[g][ni] = *(const f16x8*)&Bs[(g * 128 + wn + ni * 16 + l15) * 32 + l4 * 8];

        #pragma unroll
        for (int mi = 0; mi < 4; ++mi)
            #pragma unroll
            for (int g = 0; g < 3; ++g)
                #pragma unroll
                for (int ni = 0; ni < 2; ++ni)
                    acc[mi][g][ni] = __builtin_amdgcn_mfma_f32_16x16x32_f16(
                        af[mi], bf[g][ni], acc[mi][g][ni], 0, 0, 0);
        __syncthreads();
    }

    float bhh_[3][2], bih_[3][2], gr_[3][2];
    #pragma unroll
    for (int ni = 0; ni < 2; ++ni) {
        const int col = c0 + wn + ni * 16 + l15;
        #pragma unroll
        for (int g = 0; g < 3; ++g) {
            bhh_[g][ni] = b_hh[col + g * SH];
            bih_[g][ni] = b_ih[col + g * SH];
            gr_[g][ni]  = g_raw[col + g * SH];
        }
    }
    #pragma unroll
    for (int mi = 0; mi < 4; ++mi) {
        #pragma unroll
        for (int j = 0; j < 4; ++j) {
            const int row = m0 + wm + mi * 16 + l4 * 4 + j;
            const float bt = beta[row];
            #pragma unroll
            for (int ni = 0; ni < 2; ++ni) {
                const int col = c0 + wn + ni * 16 + l15;
                const float hp = (float)h16[(size_t)row * SH + col];
                const float ghr = acc[mi][0][ni][j] + bhh_[0][ni];
                const float ghz = acc[mi][1][ni][j] + bhh_[1][ni];
                const float ghn = acc[mi][2][ni][j] + bhh_[2][ni];
                const float gir = fmaf(bt, gr_[0][ni], bih_[0][ni]);
                const float giz = fmaf(bt, gr_[1][ni], bih_[1][ni]);
                const float gin = fmaf(bt, gr_[2][ni], bih_[2][ni]);
                const float r = sigmoid_fast(gir + ghr);
                const float z = sigmoid_fast(giz + ghz);
                const float n = tanh_fast(fmaf(r, ghn, gin));
                out[1 + (size_t)row * SH + col] = (1.0f - z) * n + z * hp;
            }
        }
    }
}

// ---------------------------------------------------------------------------
extern "C" void kernel_launch(void* const* d_in, const int* in_sizes, int n_in,
                              void* d_out, int out_size, void* d_ws, size_t ws_size,
                              hipStream_t stream) {
    const int*   topic     = (const int*)d_in[0];
    const float* knowledge = (const float*)d_in[1];
    const float* score     = (const float*)d_in[2];
    const float* emb       = (const float*)d_in[3];
    const float* Wih_f     = (const float*)d_in[4];
    const float* Whh_f     = (const float*)d_in[5];
    const float* bih_f     = (const float*)d_in[6];
    const float* bhh_f     = (const float*)d_in[7];
    const float* Wih_b     = (const float*)d_in[8];
    const float* Whh_b     = (const float*)d_in[9];
    const float* bih_b     = (const float*)d_in[10];
    const float* bhh_b     = (const float*)d_in[11];
    const float* Wk        = (const float*)d_in[12];
    const float* bk        = (const float*)d_in[13];
    const float* km        = (const float*)d_in[14];
    const float* h0        = (const float*)d_in[15];
    const float* Ws        = (const float*)d_in[16];
    const float* bs        = (const float*)d_in[17];
    const float* Wih_s     = (const float*)d_in[18];
    const float* Whh_s     = (const float*)d_in[19];
    const float* bih_s     = (const float*)d_in[20];
    const float* bhh_s     = (const float*)d_in[21];

    float* out = (float*)d_out;
    float* ws  = (float*)d_ws;

    // workspace layout (floats)
    float* v     = ws + 0;       // 256
    float* kn    = ws + 256;     // 64
    float* alpha = ws + 320;     // 16384
    float* beta  = ws + 16704;   // 16384
    float* part  = ws + 33088;   // 128*512 = 65536
    float* g_raw = ws + 98624;   // 1536
    float* gi_ws = ws + 100672;  // 2*64*384 (ends 149824 floats ~= 599 KB)

    const size_t H16_OFF = 655360;                           // 640 KB
    const size_t W16_OFF = H16_OFF + (size_t)KCNT * SH * 2;  // +16 MB
    _Float16* h16 = (_Float16*)((char*)d_ws + H16_OFF);
    _Float16* W16 = (_Float16*)((char*)d_ws + W16_OFF);

    prep_kernel<<<GRID_PREP, 384, 0, stream>>>(
        h0, h16, Whh_s, W16, topic, emb, Wih_f, bih_f, Wih_b, bih_b, gi_ws,
        Wk, bk, knowledge, kn);
    topic_gru_seq_kernel<<<2, 1024, 0, stream>>>(Whh_f, bhh_f, Whh_b, bhh_b,
                                                 gi_ws, v);
    alpha_kernel<<<KCNT * 64 / 256, 256, 0, stream>>>(km, kn, alpha);
    softmax_kernel<<<1, 1024, 0, stream>>>(alpha, beta);
    hkp_gih_kernel<<<320, 512, 0, stream>>>(beta, h16, part, Wih_s, v, score,
                                            g_raw);
    slot_gru_mfma_kernel<<<SLOT_BLOCKS + 1, 512, 0, stream>>>(
        h16, W16, beta, g_raw, bih_s, bhh_s, part, v, Ws, bs, out);
}

// Round 6
// 305.586 us; speedup vs baseline: 1.0180x; 1.0180x over previous
//
#include <hip/hip_runtime.h>
#include <math.h>

// Round 6: ONE change vs round 5 — pin topic_gru's W-slice registers with
// asm volatile("" : "+v"(...)). VGPR=52 last round proved the allocator
// rematerializes loop-invariant W loads (3rd occurrence); an asm output
// cannot be rematerialized, forcing residency. Everything else identical
// so the next profile cleanly exposes slot_gru_mfma's true duration.

#define SEQ 64
#define EMB 128
#define TH 128
#define G3 384
#define KCNT 16384
#define KE 64
#define SH 512
#define GS3 1536
#define INS 513

#define N8H (KCNT * SH / 8)      // 1048576
#define N8W (GS3 * SH / 8)       // 98304
#define NB_CVT_H 2731            // ceil(N8H/384)
#define NB_CVT_W 256             // N8W/384
#define NB_GI 128
#define NB_KN 64
#define GRID_PREP (NB_CVT_H + NB_CVT_W + NB_GI + NB_KN)

#define SLOT_BLOCKS 512          // 128 Mtiles x 4 Ntiles

typedef _Float16 f16x8 __attribute__((ext_vector_type(8)));
typedef float f32x4 __attribute__((ext_vector_type(4)));

__device__ __forceinline__ float sigmoidf_(float x) {
    return 1.0f / (1.0f + expf(-x));
}
__device__ __forceinline__ float sigmoid_fast(float x) {
    return 1.0f / (1.0f + __expf(-x));   // inf-safe
}
__device__ __forceinline__ float tanh_fast(float x) {
    return 2.0f / (1.0f + __expf(-2.0f * x)) - 1.0f;  // inf-safe
}

__device__ __forceinline__ void gl_lds16(const void* g, void* l) {
    __builtin_amdgcn_global_load_lds(
        (const __attribute__((address_space(1))) unsigned int*)g,
        (__attribute__((address_space(3))) unsigned int*)l, 16, 0, 0);
}

// ---------------------------------------------------------------------------
// PREP (one dispatch, 384-thr blocks, block-range demux):
//   [0, 2731)            cvt h0 -> h16
//   [2731, 2987)         cvt Whh_s -> W16
//   [2987, 3115)         topic_gi  (block = (t, dir))
//   [3115, 3179)         kn rows
// ---------------------------------------------------------------------------
__global__ __launch_bounds__(384) void prep_kernel(
    const float* __restrict__ h0, _Float16* __restrict__ h16,
    const float* __restrict__ Whh_s, _Float16* __restrict__ W16,
    const int* __restrict__ topic, const float* __restrict__ emb,
    const float* __restrict__ Wih_f, const float* __restrict__ bih_f,
    const float* __restrict__ Wih_b, const float* __restrict__ bih_b,
    float* __restrict__ gi_ws,
    const float* __restrict__ Wk, const float* __restrict__ bk,
    const float* __restrict__ knowledge, float* __restrict__ kn)
{
    __shared__ float red[8];
    const int b = blockIdx.x;
    const int tid = threadIdx.x;

    if (b < NB_CVT_H + NB_CVT_W) {
        const bool isH = b < NB_CVT_H;
        const float* s = isH ? h0 : Whh_s;
        _Float16* d = isH ? h16 : W16;
        const int n8 = isH ? N8H : N8W;
        const int i = (isH ? b : b - NB_CVT_H) * 384 + tid;
        if (i < n8) {
            const float4* s4 = (const float4*)s + (size_t)i * 2;
            const float4 a = s4[0], c = s4[1];
            f16x8 o;
            o[0] = (_Float16)a.x; o[1] = (_Float16)a.y;
            o[2] = (_Float16)a.z; o[3] = (_Float16)a.w;
            o[4] = (_Float16)c.x; o[5] = (_Float16)c.y;
            o[6] = (_Float16)c.z; o[7] = (_Float16)c.w;
            *(f16x8*)(d + (size_t)i * 8) = o;
        }
        return;
    }
    if (b < NB_CVT_H + NB_CVT_W + NB_GI) {
        const int idx = b - (NB_CVT_H + NB_CVT_W);
        const int t = idx & 63;
        const int dir = idx >> 6;
        const int g = tid;
        const float* Wih = dir ? Wih_b : Wih_f;
        const float* bih = dir ? bih_b : bih_f;
        const int tok = topic[dir ? (SEQ - 1 - t) : t];
        const float4* e4 = (const float4*)(emb + (size_t)tok * EMB);
        const float4* w4 = (const float4*)(Wih + (size_t)g * EMB);
        float acc = bih[g];
        #pragma unroll
        for (int q = 0; q < EMB / 4; ++q) {
            float4 w = w4[q], e = e4[q];
            acc += w.x * e.x + w.y * e.y + w.z * e.z + w.w * e.w;
        }
        gi_ws[((size_t)dir * SEQ + t) * G3 + g] = acc;
        return;
    }
    // kn rows
    {
        const int row = b - (NB_CVT_H + NB_CVT_W + NB_GI);
        const float4* w4 = (const float4*)(Wk + (size_t)row * KCNT);
        const float4* k4 = (const float4*)knowledge;
        float acc = 0.0f;
        for (int i = tid; i < KCNT / 4; i += 384) {
            float4 w = w4[i], k = k4[i];
            acc += w.x * k.x + w.y * k.y + w.z * k.z + w.w * k.w;
        }
        #pragma unroll
        for (int off = 32; off; off >>= 1) acc += __shfl_xor(acc, off);
        if ((tid & 63) == 0) red[tid >> 6] = acc;
        __syncthreads();
        if (tid == 0) {
            float t = bk[row];
            #pragma unroll
            for (int wv = 0; wv < 6; ++wv) t += red[wv];
            kn[row] = t;
        }
    }
}

// ---------------------------------------------------------------------------
// K1: sequential topic GRU. grid 2, 1024 threads.
// thread (j = tid>>3, s = tid&7): output row j, k-slice [s*16, s*16+16).
// W slice = 12 float4 = 48 VGPRs, PINNED via asm (+v) so the allocator
// cannot rematerialize the loads inside the 64-step loop (VGPR=52 in r5
// proved it did exactly that).
// ---------------------------------------------------------------------------
__global__ __launch_bounds__(1024) void topic_gru_seq_kernel(
    const float* __restrict__ Whh_f, const float* __restrict__ bhh_f,
    const float* __restrict__ Whh_b, const float* __restrict__ bhh_b,
    const float* __restrict__ gi_ws, float* __restrict__ v_out)
{
    const int dir = blockIdx.x;
    const float* __restrict__ Whh = dir ? Whh_b : Whh_f;
    const float* __restrict__ bhh = dir ? bhh_b : bhh_f;
    const float* __restrict__ gi = gi_ws + (size_t)dir * SEQ * G3;
    const int tid = threadIdx.x;
    const int j = tid >> 3;
    const int s = tid & 7;

    __shared__ float gi_lds[SEQ * G3];   // 96 KB
    __shared__ float hls[2][TH];

    {
        const float4* src = (const float4*)gi;
        float4* dst = (float4*)gi_lds;
        #pragma unroll
        for (int i = 0; i < 6; ++i)
            dst[tid + i * 1024] = src[tid + i * 1024];
    }

    float4 wr[4], wz[4], wn[4];
    {
        const float4* pr = (const float4*)(Whh + (size_t)j * TH + s * 16);
        const float4* pz = (const float4*)(Whh + (size_t)(TH + j) * TH + s * 16);
        const float4* pn = (const float4*)(Whh + (size_t)(2 * TH + j) * TH + s * 16);
        #pragma unroll
        for (int q = 0; q < 4; ++q) { wr[q] = pr[q]; wz[q] = pz[q]; wn[q] = pn[q]; }
    }
    // Pin: asm outputs cannot be rematerialized -> W stays in registers.
    #pragma unroll
    for (int q = 0; q < 4; ++q) {
        asm volatile("" : "+v"(wr[q].x), "+v"(wr[q].y), "+v"(wr[q].z), "+v"(wr[q].w));
        asm volatile("" : "+v"(wz[q].x), "+v"(wz[q].y), "+v"(wz[q].z), "+v"(wz[q].w));
        asm volatile("" : "+v"(wn[q].x), "+v"(wn[q].y), "+v"(wn[q].z), "+v"(wn[q].w));
    }
    const float bhr = bhh[j], bhz = bhh[j + TH], bhn = bhh[j + 2 * TH];

    if (tid < TH) hls[0][tid] = 0.0f;
    float h_old = 0.0f, vmax = -1e30f;
    __syncthreads();

    int cur = 0;
    for (int t = 0; t < SEQ; ++t) {
        const float4* h4 = (const float4*)(&hls[cur][s * 16]);
        float ar0 = 0.f, ar1 = 0.f, az0 = 0.f, az1 = 0.f, an0 = 0.f, an1 = 0.f;
        #pragma unroll
        for (int q = 0; q < 4; q += 2) {
            const float4 h0v = h4[q], h1v = h4[q + 1];
            ar0 = fmaf(wr[q].x, h0v.x, ar0); ar0 = fmaf(wr[q].y, h0v.y, ar0);
            ar0 = fmaf(wr[q].z, h0v.z, ar0); ar0 = fmaf(wr[q].w, h0v.w, ar0);
            ar1 = fmaf(wr[q+1].x, h1v.x, ar1); ar1 = fmaf(wr[q+1].y, h1v.y, ar1);
            ar1 = fmaf(wr[q+1].z, h1v.z, ar1); ar1 = fmaf(wr[q+1].w, h1v.w, ar1);
            az0 = fmaf(wz[q].x, h0v.x, az0); az0 = fmaf(wz[q].y, h0v.y, az0);
            az0 = fmaf(wz[q].z, h0v.z, az0); az0 = fmaf(wz[q].w, h0v.w, az0);
            az1 = fmaf(wz[q+1].x, h1v.x, az1); az1 = fmaf(wz[q+1].y, h1v.y, az1);
            az1 = fmaf(wz[q+1].z, h1v.z, az1); az1 = fmaf(wz[q+1].w, h1v.w, az1);
            an0 = fmaf(wn[q].x, h0v.x, an0); an0 = fmaf(wn[q].y, h0v.y, an0);
            an0 = fmaf(wn[q].z, h0v.z, an0); an0 = fmaf(wn[q].w, h0v.w, an0);
            an1 = fmaf(wn[q+1].x, h1v.x, an1); an1 = fmaf(wn[q+1].y, h1v.y, an1);
            an1 = fmaf(wn[q+1].z, h1v.z, an1); an1 = fmaf(wn[q+1].w, h1v.w, an1);
        }
        float ar = ar0 + ar1, az = az0 + az1, an = an0 + an1;
        ar += __shfl_xor(ar, 1); ar += __shfl_xor(ar, 2); ar += __shfl_xor(ar, 4);
        az += __shfl_xor(az, 1); az += __shfl_xor(az, 2); az += __shfl_xor(az, 4);
        an += __shfl_xor(an, 1); an += __shfl_xor(an, 2); an += __shfl_xor(an, 4);
        if (s == 0) {
            const float gir = gi_lds[t * G3 + j];
            const float giz = gi_lds[t * G3 + j + TH];
            const float gin = gi_lds[t * G3 + j + 2 * TH];
            const float r = sigmoidf_(gir + ar + bhr);
            const float z = sigmoidf_(giz + az + bhz);
            const float n = tanhf(fmaf(r, an + bhn, gin));
            const float hn = (1.0f - z) * n + z * h_old;
            hls[cur ^ 1][j] = hn;
            h_old = hn;
            vmax = fmaxf(vmax, hn);
        }
        __syncthreads();
        cur ^= 1;
    }
    if (s == 0) v_out[dir * TH + j] = vmax;
}

// ---------------------------------------------------------------------------
// K3: alpha[row] = dot(km[row,:64], kn)
// ---------------------------------------------------------------------------
__global__ __launch_bounds__(256) void alpha_kernel(
    const float* __restrict__ km, const float* __restrict__ kn,
    float* __restrict__ alpha)
{
    const int idx = blockIdx.x * 256 + threadIdx.x;
    const int row = idx >> 6;
    const int lane = idx & 63;
    float p = km[(size_t)row * KE + lane] * kn[lane];
    #pragma unroll
    for (int off = 32; off; off >>= 1) p += __shfl_xor(p, off);
    if (lane == 0) alpha[row] = p;
}

// ---------------------------------------------------------------------------
// K4: beta = softmax(alpha) over 16384
// ---------------------------------------------------------------------------
__global__ __launch_bounds__(1024) void softmax_kernel(
    const float* __restrict__ alpha, float* __restrict__ beta)
{
    const int tid = threadIdx.x;
    float vals[16];
    float m = -1e30f;
    #pragma unroll
    for (int i = 0; i < 16; ++i) {
        vals[i] = alpha[tid + i * 1024];
        m = fmaxf(m, vals[i]);
    }
    #pragma unroll
    for (int off = 32; off; off >>= 1) m = fmaxf(m, __shfl_xor(m, off));
    __shared__ float red[16];
    if ((tid & 63) == 0) red[tid >> 6] = m;
    __syncthreads();
    float M = red[0];
    #pragma unroll
    for (int wv = 1; wv < 16; ++wv) M = fmaxf(M, red[wv]);
    __syncthreads();
    float s = 0.0f;
    #pragma unroll
    for (int i = 0; i < 16; ++i) {
        vals[i] = expf(vals[i] - M);
        s += vals[i];
    }
    #pragma unroll
    for (int off = 32; off; off >>= 1) s += __shfl_xor(s, off);
    if ((tid & 63) == 0) red[tid >> 6] = s;
    __syncthreads();
    float S = 0.0f;
    #pragma unroll
    for (int wv = 0; wv < 16; ++wv) S += red[wv];
    const float inv = 1.0f / S;
    #pragma unroll
    for (int i = 0; i < 16; ++i) beta[tid + i * 1024] = vals[i] * inv;
}

// ---------------------------------------------------------------------------
// K5+K7 fused (512 thr): blocks [0,128) = hkp partials (fp16 h);
// blocks [128, 320) = gih rows (x_in computed inline from v/score).
// ---------------------------------------------------------------------------
__global__ __launch_bounds__(512) void hkp_gih_kernel(
    const float* __restrict__ beta, const _Float16* __restrict__ h16,
    float* __restrict__ part,
    const float* __restrict__ Wih_s, const float* __restrict__ v,
    const float* __restrict__ score, float* __restrict__ g_raw)
{
    const int b = blockIdx.x;
    const int tid = threadIdx.x;
    if (b < 128) {
        const int j = tid;
        const int r0 = b * (KCNT / 128);
        float acc = 0.0f;
        for (int r = 0; r < KCNT / 128; ++r)
            acc = fmaf(beta[r0 + r], (float)h16[(size_t)(r0 + r) * SH + j], acc);
        part[(size_t)b * SH + j] = acc;
        return;
    }
    // gih: 8 rows per block, one wave per row
    const int gid = b - 128;
    const int row = gid * 8 + (tid >> 6);
    const int lane = tid & 63;
    const float sc = score[0];
    const float pos = (sc >= 0.5f) ? 1.0f : 0.0f;
    const float om = 1.0f - pos;
    const float* wrow = Wih_s + (size_t)row * INS;
    float acc = 0.0f;
    for (int k = lane; k < INS; k += 64) {
        const float xv = (k < 256) ? v[k] * pos
                       : (k < 512) ? v[k - 256] * om : sc;
        acc = fmaf(wrow[k], xv, acc);
    }
    #pragma unroll
    for (int off = 32; off; off >>= 1) acc += __shfl_xor(acc, off);
    if (lane == 0) g_raw[row] = acc;
}

// ---------------------------------------------------------------------------
// K8-MFMA + score (513 blocks, 512 thr):
// blocks [0,512): gh = h @ Whh.T fp16 MFMA, fused GRU epilogue.
//   tile 128 rows x 128 cols x 3 gates, BK=32, 8 waves (2m x 4n).
// block 512: predict_score -> out[0] (reduce hkp parts + dot).
// ---------------------------------------------------------------------------
__global__ __launch_bounds__(512, 1) void slot_gru_mfma_kernel(
    const _Float16* __restrict__ h16, // [16384,512]
    const _Float16* __restrict__ W16, // [1536,512]
    const float* __restrict__ beta,   // [16384]
    const float* __restrict__ g_raw,  // [1536]
    const float* __restrict__ b_ih,   // [1536]
    const float* __restrict__ b_hh,   // [1536]
    const float* __restrict__ part,   // [128,512]
    const float* __restrict__ v,      // [256]
    const float* __restrict__ Ws, const float* __restrict__ bs,
    float* __restrict__ out)          // out[0]=score, out+1 = h_new
{
    __shared__ _Float16 As[128 * 32];      // [row][k]   8 KB
    __shared__ _Float16 Bs[384 * 32];      // [g*128+col][k]  24 KB

    const int tid = threadIdx.x;

    if (blockIdx.x == SLOT_BLOCKS) {       // score block
        float* red = (float*)As;
        float hkp = 0.0f;
        for (int b = 0; b < 128; ++b) hkp += part[(size_t)b * SH + tid];
        float contrib = hkp * Ws[256 + tid];
        if (tid < 256) contrib += v[tid] * Ws[tid];
        #pragma unroll
        for (int off = 32; off; off >>= 1) contrib += __shfl_xor(contrib, off);
        if ((tid & 63) == 0) red[tid >> 6] = contrib;
        __syncthreads();
        if (tid == 0) {
            float p = bs[0];
            #pragma unroll
            for (int wv = 0; wv < 8; ++wv) p += red[wv];
            out[0] = p;
        }
        return;
    }

    const int lane = tid & 63;
    const int wv  = tid >> 6;
    const int wm  = (wv >> 2) * 64;
    const int wn  = (wv & 3) * 32;
    const int nt  = blockIdx.x & 3;
    const int mt  = blockIdx.x >> 2;
    const int m0  = mt * 128;
    const int c0  = nt * 128;
    const int l15 = lane & 15;
    const int l4  = lane >> 4;

    f32x4 acc[4][3][2];
    #pragma unroll
    for (int mi = 0; mi < 4; ++mi)
        #pragma unroll
        for (int g = 0; g < 3; ++g)
            #pragma unroll
            for (int ni = 0; ni < 2; ++ni)
                acc[mi][g][ni] = (f32x4){0.f, 0.f, 0.f, 0.f};

    for (int k0 = 0; k0 < SH; k0 += 32) {
        {   // A: 128 rows x 32 k = 512 16B chunks, 1/thread
            const int r = tid >> 2, c = tid & 3;
            gl_lds16(h16 + (size_t)(m0 + r) * SH + k0 + c * 8, &As[tid * 8]);
        }
        #pragma unroll
        for (int p = 0; p < 3; ++p) {   // B: 384 rows x 32 k = 1536 chunks
            const int idx = tid + p * 512;
            const int r = idx >> 2, c = idx & 3;
            const int g = r >> 7, wcol = r & 127;
            gl_lds16(W16 + (size_t)(g * SH + c0 + wcol) * SH + k0 + c * 8,
                     &Bs[idx * 8]);
        }
        __syncthreads();

        f16x8 af[4], bf[3][2];
        #pragma unroll
        for (int mi = 0; mi < 4; ++mi)
            af[mi] = *(const f16x8*)&As[(wm + mi * 16 + l15) * 32 + l4 * 8];
        #pragma unroll
        for (int g = 0; g < 3; ++g)
            #pragma unroll
            for (int ni = 0; ni < 2; ++ni)
                bf[g][ni] = *(const f16x8*)&Bs[(g * 128 + wn + ni * 16 + l15) * 32 + l4 * 8];

        #pragma unroll
        for (int mi = 0; mi < 4; ++mi)
            #pragma unroll
            for (int g = 0; g < 3; ++g)
                #pragma unroll
                for (int ni = 0; ni < 2; ++ni)
                    acc[mi][g][ni] = __builtin_amdgcn_mfma_f32_16x16x32_f16(
                        af[mi], bf[g][ni], acc[mi][g][ni], 0, 0, 0);
        __syncthreads();
    }

    float bhh_[3][2], bih_[3][2], gr_[3][2];
    #pragma unroll
    for (int ni = 0; ni < 2; ++ni) {
        const int col = c0 + wn + ni * 16 + l15;
        #pragma unroll
        for (int g = 0; g < 3; ++g) {
            bhh_[g][ni] = b_hh[col + g * SH];
            bih_[g][ni] = b_ih[col + g * SH];
            gr_[g][ni]  = g_raw[col + g * SH];
        }
    }
    #pragma unroll
    for (int mi = 0; mi < 4; ++mi) {
        #pragma unroll
        for (int j = 0; j < 4; ++j) {
            const int row = m0 + wm + mi * 16 + l4 * 4 + j;
            const float bt = beta[row];
            #pragma unroll
            for (int ni = 0; ni < 2; ++ni) {
                const int col = c0 + wn + ni * 16 + l15;
                const float hp = (float)h16[(size_t)row * SH + col];
                const float ghr = acc[mi][0][ni][j] + bhh_[0][ni];
                const float ghz = acc[mi][1][ni][j] + bhh_[1][ni];
                const float ghn = acc[mi][2][ni][j] + bhh_[2][ni];
                const float gir = fmaf(bt, gr_[0][ni], bih_[0][ni]);
                const float giz = fmaf(bt, gr_[1][ni], bih_[1][ni]);
                const float gin = fmaf(bt, gr_[2][ni], bih_[2][ni]);
                const float r = sigmoid_fast(gir + ghr);
                const float z = sigmoid_fast(giz + ghz);
                const float n = tanh_fast(fmaf(r, ghn, gin));
                out[1 + (size_t)row * SH + col] = (1.0f - z) * n + z * hp;
            }
        }
    }
}

// ---------------------------------------------------------------------------
extern "C" void kernel_launch(void* const* d_in, const int* in_sizes, int n_in,
                              void* d_out, int out_size, void* d_ws, size_t ws_size,
                              hipStream_t stream) {
    const int*   topic     = (const int*)d_in[0];
    const float* knowledge = (const float*)d_in[1];
    const float* score     = (const float*)d_in[2];
    const float* emb       = (const float*)d_in[3];
    const float* Wih_f     = (const float*)d_in[4];
    const float* Whh_f     = (const float*)d_in[5];
    const float* bih_f     = (const float*)d_in[6];
    const float* bhh_f     = (const float*)d_in[7];
    const float* Wih_b     = (const float*)d_in[8];
    const float* Whh_b     = (const float*)d_in[9];
    const float* bih_b     = (const float*)d_in[10];
    const float* bhh_b     = (const float*)d_in[11];
    const float* Wk        = (const float*)d_in[12];
    const float* bk        = (const float*)d_in[13];
    const float* km        = (const float*)d_in[14];
    const float* h0        = (const float*)d_in[15];
    const float* Ws        = (const float*)d_in[16];
    const float* bs        = (const float*)d_in[17];
    const float* Wih_s     = (const float*)d_in[18];
    const float* Whh_s     = (const float*)d_in[19];
    const float* bih_s     = (const float*)d_in[20];
    const float* bhh_s     = (const float*)d_in[21];

    float* out = (float*)d_out;
    float* ws  = (float*)d_ws;

    // workspace layout (floats)
    float* v     = ws + 0;       // 256
    float* kn    = ws + 256;     // 64
    float* alpha = ws + 320;     // 16384
    float* beta  = ws + 16704;   // 16384
    float* part  = ws + 33088;   // 128*512 = 65536
    float* g_raw = ws + 98624;   // 1536
    float* gi_ws = ws + 100672;  // 2*64*384 (ends 149824 floats ~= 599 KB)

    const size_t H16_OFF = 655360;                           // 640 KB
    const size_t W16_OFF = H16_OFF + (size_t)KCNT * SH * 2;  // +16 MB
    _Float16* h16 = (_Float16*)((char*)d_ws + H16_OFF);
    _Float16* W16 = (_Float16*)((char*)d_ws + W16_OFF);

    prep_kernel<<<GRID_PREP, 384, 0, stream>>>(
        h0, h16, Whh_s, W16, topic, emb, Wih_f, bih_f, Wih_b, bih_b, gi_ws,
        Wk, bk, knowledge, kn);
    topic_gru_seq_kernel<<<2, 1024, 0, stream>>>(Whh_f, bhh_f, Whh_b, bhh_b,
                                                 gi_ws, v);
    alpha_kernel<<<KCNT * 64 / 256, 256, 0, stream>>>(km, kn, alpha);
    softmax_kernel<<<1, 1024, 0, stream>>>(alpha, beta);
    hkp_gih_kernel<<<320, 512, 0, stream>>>(beta, h16, part, Wih_s, v, score,
                                            g_raw);
    slot_gru_mfma_kernel<<<SLOT_BLOCKS + 1, 512, 0, stream>>>(
        h16, W16, beta, g_raw, bih_s, bhh_s, part, v, Ws, bs, out);
}

// Round 8
// 304.076 us; speedup vs baseline: 1.0230x; 1.0050x over previous
//
#include <hip/hip_runtime.h>
#include <math.h>

// Round 8 = round 7 resubmission (broker timeout, never ran).
// (1) topic_gru: W in LDS fp16 (k-outer layout, conflict-free), fdot2,
// gate phase wave-uniform in waves 0-1 only, __expf gates. The
// register-cache approach is dead: 3 rounds proved the allocator drops it.
// (2) slot_gru: chunk layouts [c][row] / [g][c][col] make all frag
// ds_read_b128 lane-contiguous (16B stride) -> kills the 8-way conflict
// of the 64B-row-stride layout; gl_lds16 dests stay linear (m104).

#define SEQ 64
#define EMB 128
#define TH 128
#define G3 384
#define KCNT 16384
#define KE 64
#define SH 512
#define GS3 1536
#define INS 513

#define N8H (KCNT * SH / 8)      // 1048576
#define N8W (GS3 * SH / 8)       // 98304
#define NB_CVT_H 2731            // ceil(N8H/384)
#define NB_CVT_W 256             // N8W/384
#define NB_GI 128
#define NB_KN 64
#define GRID_PREP (NB_CVT_H + NB_CVT_W + NB_GI + NB_KN)

#define SLOT_BLOCKS 512          // 128 Mtiles x 4 Ntiles

typedef _Float16 f16x8 __attribute__((ext_vector_type(8)));
typedef _Float16 f16x2 __attribute__((ext_vector_type(2)));
typedef float f32x4 __attribute__((ext_vector_type(4)));

#if __has_builtin(__builtin_amdgcn_fdot2)
#define DOT2(a, b, c) __builtin_amdgcn_fdot2((a), (b), (c), false)
#else
#define DOT2(a, b, c) fmaf((float)(a)[1], (float)(b)[1], \
                           fmaf((float)(a)[0], (float)(b)[0], (c)))
#endif

__device__ __forceinline__ float sigmoid_fast(float x) {
    return 1.0f / (1.0f + __expf(-x));   // inf-safe
}
__device__ __forceinline__ float tanh_fast(float x) {
    return 2.0f / (1.0f + __expf(-2.0f * x)) - 1.0f;  // inf-safe
}

__device__ __forceinline__ void gl_lds16(const void* g, void* l) {
    __builtin_amdgcn_global_load_lds(
        (const __attribute__((address_space(1))) unsigned int*)g,
        (__attribute__((address_space(3))) unsigned int*)l, 16, 0, 0);
}

// ---------------------------------------------------------------------------
// PREP (one dispatch, 384-thr blocks, block-range demux):
//   [0, 2731)            cvt h0 -> h16
//   [2731, 2987)         cvt Whh_s -> W16
//   [2987, 3115)         topic_gi  (block = (t, dir))
//   [3115, 3179)         kn rows
// ---------------------------------------------------------------------------
__global__ __launch_bounds__(384) void prep_kernel(
    const float* __restrict__ h0, _Float16* __restrict__ h16,
    const float* __restrict__ Whh_s, _Float16* __restrict__ W16,
    const int* __restrict__ topic, const float* __restrict__ emb,
    const float* __restrict__ Wih_f, const float* __restrict__ bih_f,
    const float* __restrict__ Wih_b, const float* __restrict__ bih_b,
    float* __restrict__ gi_ws,
    const float* __restrict__ Wk, const float* __restrict__ bk,
    const float* __restrict__ knowledge, float* __restrict__ kn)
{
    __shared__ float red[8];
    const int b = blockIdx.x;
    const int tid = threadIdx.x;

    if (b < NB_CVT_H + NB_CVT_W) {
        const bool isH = b < NB_CVT_H;
        const float* s = isH ? h0 : Whh_s;
        _Float16* d = isH ? h16 : W16;
        const int n8 = isH ? N8H : N8W;
        const int i = (isH ? b : b - NB_CVT_H) * 384 + tid;
        if (i < n8) {
            const float4* s4 = (const float4*)s + (size_t)i * 2;
            const float4 a = s4[0], c = s4[1];
            f16x8 o;
            o[0] = (_Float16)a.x; o[1] = (_Float16)a.y;
            o[2] = (_Float16)a.z; o[3] = (_Float16)a.w;
            o[4] = (_Float16)c.x; o[5] = (_Float16)c.y;
            o[6] = (_Float16)c.z; o[7] = (_Float16)c.w;
            *(f16x8*)(d + (size_t)i * 8) = o;
        }
        return;
    }
    if (b < NB_CVT_H + NB_CVT_W + NB_GI) {
        const int idx = b - (NB_CVT_H + NB_CVT_W);
        const int t = idx & 63;
        const int dir = idx >> 6;
        const int g = tid;
        const float* Wih = dir ? Wih_b : Wih_f;
        const float* bih = dir ? bih_b : bih_f;
        const int tok = topic[dir ? (SEQ - 1 - t) : t];
        const float4* e4 = (const float4*)(emb + (size_t)tok * EMB);
        const float4* w4 = (const float4*)(Wih + (size_t)g * EMB);
        float acc = bih[g];
        #pragma unroll
        for (int q = 0; q < EMB / 4; ++q) {
            float4 w = w4[q], e = e4[q];
            acc += w.x * e.x + w.y * e.y + w.z * e.z + w.w * e.w;
        }
        gi_ws[((size_t)dir * SEQ + t) * G3 + g] = acc;
        return;
    }
    // kn rows
    {
        const int row = b - (NB_CVT_H + NB_CVT_W + NB_GI);
        const float4* w4 = (const float4*)(Wk + (size_t)row * KCNT);
        const float4* k4 = (const float4*)knowledge;
        float acc = 0.0f;
        for (int i = tid; i < KCNT / 4; i += 384) {
            float4 w = w4[i], k = k4[i];
            acc += w.x * k.x + w.y * k.y + w.z * k.z + w.w * k.w;
        }
        #pragma unroll
        for (int off = 32; off; off >>= 1) acc += __shfl_xor(acc, off);
        if ((tid & 63) == 0) red[tid >> 6] = acc;
        __syncthreads();
        if (tid == 0) {
            float t = bk[row];
            #pragma unroll
            for (int wv = 0; wv < 6; ++wv) t += red[wv];
            kn[row] = t;
        }
    }
}

// ---------------------------------------------------------------------------
// K1: sequential topic GRU. grid 2, 1024 threads.
// thread (j = tid&127, s = tid>>7): row j, k-slice [s*16, s*16+16).
// W staged ONCE into LDS fp16, chunk layout [g][kchunk(16)][row(128)] so
// per-step frag reads are lane-contiguous 16B (conflict-free).
// Gate phase: tid<128 == waves 0,1 only (wave-uniform branch) -> the other
// 14 waves never issue transcendental code. gi loaded from global,
// issued at loop top, consumed after the barrier (latency hidden).
// ---------------------------------------------------------------------------
__global__ __launch_bounds__(1024) void topic_gru_seq_kernel(
    const float* __restrict__ Whh_f, const float* __restrict__ bhh_f,
    const float* __restrict__ Whh_b, const float* __restrict__ bhh_b,
    const float* __restrict__ gi_ws, float* __restrict__ v_out)
{
    const int dir = blockIdx.x;
    const float* __restrict__ Whh = dir ? Whh_b : Whh_f;
    const float* __restrict__ bhh = dir ? bhh_b : bhh_f;
    const float* __restrict__ gi = gi_ws + (size_t)dir * SEQ * G3;
    const int tid = threadIdx.x;
    const int j = tid & 127;
    const int s = tid >> 7;

    __shared__ _Float16 Wl[3 * 16 * TH * 8];   // [g][c][row] chunks of 8h, 96KB
    __shared__ float part[3 * TH * 9];         // [g][row][s pad 9], 13.5KB
    __shared__ _Float16 hls[2][TH];

    // stage W: chunk (g, c, row) <- W[g*128+row][c*8 .. c*8+8), 6144 chunks
    #pragma unroll
    for (int it = 0; it < 6; ++it) {
        const int i = tid + it * 1024;
        const int gc = i >> 7;            // g*16 + c
        const int row = i & 127;
        const int g = gc >> 4, c = gc & 15;
        const float4* s4 = (const float4*)(Whh + ((size_t)(g * TH + row)) * TH + c * 8);
        const float4 a = s4[0], bb = s4[1];
        f16x8 o;
        o[0] = (_Float16)a.x;  o[1] = (_Float16)a.y;
        o[2] = (_Float16)a.z;  o[3] = (_Float16)a.w;
        o[4] = (_Float16)bb.x; o[5] = (_Float16)bb.y;
        o[6] = (_Float16)bb.z; o[7] = (_Float16)bb.w;
        *(f16x8*)&Wl[(size_t)i * 8] = o;
    }
    if (tid < TH) hls[0][tid] = (_Float16)0.0f;

    const bool gate_lane = (tid < TH);   // waves 0,1 (wave-uniform)
    float h_old = 0.0f, vmax = -1e30f;
    float bhr = 0.f, bhz = 0.f, bhn = 0.f;
    if (gate_lane) { bhr = bhh[j]; bhz = bhh[j + TH]; bhn = bhh[j + 2 * TH]; }
    __syncthreads();

    int cur = 0;
    for (int t = 0; t < SEQ; ++t) {
        float gir = 0.f, giz = 0.f, gin = 0.f;
        if (gate_lane) {                  // issue early, use after barrier
            gir = gi[t * G3 + j];
            giz = gi[t * G3 + j + TH];
            gin = gi[t * G3 + j + 2 * TH];
        }
        // phase 1: partial dot products (all 16 waves)
        union { f16x8 v; f16x2 p[4]; } hu0, hu1, wu0, wu1;
        hu0.v = *(const f16x8*)&hls[cur][s * 16];
        hu1.v = *(const f16x8*)&hls[cur][s * 16 + 8];
        #pragma unroll
        for (int g = 0; g < 3; ++g) {
            wu0.v = *(const f16x8*)&Wl[((g * 16 + 2 * s) * TH + j) * 8];
            wu1.v = *(const f16x8*)&Wl[((g * 16 + 2 * s + 1) * TH + j) * 8];
            float a0 = 0.f, a1 = 0.f;
            #pragma unroll
            for (int e = 0; e < 4; ++e) {
                a0 = DOT2(wu0.p[e], hu0.p[e], a0);
                a1 = DOT2(wu1.p[e], hu1.p[e], a1);
            }
            part[(g * TH + j) * 9 + s] = a0 + a1;
        }
        __syncthreads();
        // phase 2: gates (waves 0,1 only)
        if (gate_lane) {
            float ar = 0.f, az = 0.f, an_ = 0.f;
            #pragma unroll
            for (int q = 0; q < 8; ++q) {
                ar  += part[(0 * TH + j) * 9 + q];
                az  += part[(1 * TH + j) * 9 + q];
                an_ += part[(2 * TH + j) * 9 + q];
            }
            const float r = sigmoid_fast(gir + ar + bhr);
            const float z = sigmoid_fast(giz + az + bhz);
            const float n = tanh_fast(fmaf(r, an_ + bhn, gin));
            const float hn = (1.0f - z) * n + z * h_old;
            hls[cur ^ 1][j] = (_Float16)hn;
            h_old = hn;
            vmax = fmaxf(vmax, hn);
        }
        __syncthreads();
        cur ^= 1;
    }
    if (gate_lane) v_out[dir * TH + j] = vmax;
}

// ---------------------------------------------------------------------------
// K3: alpha[row] = dot(km[row,:64], kn)
// ---------------------------------------------------------------------------
__global__ __launch_bounds__(256) void alpha_kernel(
    const float* __restrict__ km, const float* __restrict__ kn,
    float* __restrict__ alpha)
{
    const int idx = blockIdx.x * 256 + threadIdx.x;
    const int row = idx >> 6;
    const int lane = idx & 63;
    float p = km[(size_t)row * KE + lane] * kn[lane];
    #pragma unroll
    for (int off = 32; off; off >>= 1) p += __shfl_xor(p, off);
    if (lane == 0) alpha[row] = p;
}

// ---------------------------------------------------------------------------
// K4: beta = softmax(alpha) over 16384
// ---------------------------------------------------------------------------
__global__ __launch_bounds__(1024) void softmax_kernel(
    const float* __restrict__ alpha, float* __restrict__ beta)
{
    const int tid = threadIdx.x;
    float vals[16];
    float m = -1e30f;
    #pragma unroll
    for (int i = 0; i < 16; ++i) {
        vals[i] = alpha[tid + i * 1024];
        m = fmaxf(m, vals[i]);
    }
    #pragma unroll
    for (int off = 32; off; off >>= 1) m = fmaxf(m, __shfl_xor(m, off));
    __shared__ float red[16];
    if ((tid & 63) == 0) red[tid >> 6] = m;
    __syncthreads();
    float M = red[0];
    #pragma unroll
    for (int wv = 1; wv < 16; ++wv) M = fmaxf(M, red[wv]);
    __syncthreads();
    float s = 0.0f;
    #pragma unroll
    for (int i = 0; i < 16; ++i) {
        vals[i] = expf(vals[i] - M);
        s += vals[i];
    }
    #pragma unroll
    for (int off = 32; off; off >>= 1) s += __shfl_xor(s, off);
    if ((tid & 63) == 0) red[tid >> 6] = s;
    __syncthreads();
    float S = 0.0f;
    #pragma unroll
    for (int wv = 0; wv < 16; ++wv) S += red[wv];
    const float inv = 1.0f / S;
    #pragma unroll
    for (int i = 0; i < 16; ++i) beta[tid + i * 1024] = vals[i] * inv;
}

// ---------------------------------------------------------------------------
// K5+K7 fused (512 thr): blocks [0,128) = hkp partials (fp16 h);
// blocks [128, 320) = gih rows (x_in computed inline from v/score).
// ---------------------------------------------------------------------------
__global__ __launch_bounds__(512) void hkp_gih_kernel(
    const float* __restrict__ beta, const _Float16* __restrict__ h16,
    float* __restrict__ part,
    const float* __restrict__ Wih_s, const float* __restrict__ v,
    const float* __restrict__ score, float* __restrict__ g_raw)
{
    const int b = blockIdx.x;
    const int tid = threadIdx.x;
    if (b < 128) {
        const int j = tid;
        const int r0 = b * (KCNT / 128);
        float acc = 0.0f;
        for (int r = 0; r < KCNT / 128; ++r)
            acc = fmaf(beta[r0 + r], (float)h16[(size_t)(r0 + r) * SH + j], acc);
        part[(size_t)b * SH + j] = acc;
        return;
    }
    const int gid = b - 128;
    const int row = gid * 8 + (tid >> 6);
    const int lane = tid & 63;
    const float sc = score[0];
    const float pos = (sc >= 0.5f) ? 1.0f : 0.0f;
    const float om = 1.0f - pos;
    const float* wrow = Wih_s + (size_t)row * INS;
    float acc = 0.0f;
    for (int k = lane; k < INS; k += 64) {
        const float xv = (k < 256) ? v[k] * pos
                       : (k < 512) ? v[k - 256] * om : sc;
        acc = fmaf(wrow[k], xv, acc);
    }
    #pragma unroll
    for (int off = 32; off; off >>= 1) acc += __shfl_xor(acc, off);
    if (lane == 0) g_raw[row] = acc;
}

// ---------------------------------------------------------------------------
// K8-MFMA + score (513 blocks, 512 thr):
// blocks [0,512): gh = h @ Whh.T fp16 MFMA, fused GRU epilogue.
//   Chunk layouts: As [c(4)][row(128)], Bs [g(3)][c(4)][col(128)] -> frag
//   ds_read_b128 lane-contiguous (16B stride, no 8-way conflict).
//   gl_lds16 dest linear in tid (m104); per-lane source re-derived.
// block 512: predict_score -> out[0].
// ---------------------------------------------------------------------------
__global__ __launch_bounds__(512, 1) void slot_gru_mfma_kernel(
    const _Float16* __restrict__ h16, // [16384,512]
    const _Float16* __restrict__ W16, // [1536,512]
    const float* __restrict__ beta,   // [16384]
    const float* __restrict__ g_raw,  // [1536]
    const float* __restrict__ b_ih,   // [1536]
    const float* __restrict__ b_hh,   // [1536]
    const float* __restrict__ part,   // [128,512]
    const float* __restrict__ v,      // [256]
    const float* __restrict__ Ws, const float* __restrict__ bs,
    float* __restrict__ out)          // out[0]=score, out+1 = h_new
{
    __shared__ _Float16 As[128 * 32];      // [c][row] chunks, 8 KB
    __shared__ _Float16 Bs[384 * 32];      // [g][c][col] chunks, 24 KB

    const int tid = threadIdx.x;

    if (blockIdx.x == SLOT_BLOCKS) {       // score block
        float* red = (float*)As;
        float hkp = 0.0f;
        for (int b = 0; b < 128; ++b) hkp += part[(size_t)b * SH + tid];
        float contrib = hkp * Ws[256 + tid];
        if (tid < 256) contrib += v[tid] * Ws[tid];
        #pragma unroll
        for (int off = 32; off; off >>= 1) contrib += __shfl_xor(contrib, off);
        if ((tid & 63) == 0) red[tid >> 6] = contrib;
        __syncthreads();
        if (tid == 0) {
            float p = bs[0];
            #pragma unroll
            for (int wv = 0; wv < 8; ++wv) p += red[wv];
            out[0] = p;
        }
        return;
    }

    const int lane = tid & 63;
    const int wv  = tid >> 6;
    const int wm  = (wv >> 2) * 64;
    const int wn  = (wv & 3) * 32;
    const int nt  = blockIdx.x & 3;
    const int mt  = blockIdx.x >> 2;
    const int m0  = mt * 128;
    const int c0  = nt * 128;
    const int l15 = lane & 15;
    const int l4  = lane >> 4;
    const int sc_ = tid >> 7;          // staging chunk c (0..3)
    const int sr_ = tid & 127;         // staging row/col

    f32x4 acc[4][3][2];
    #pragma unroll
    for (int mi = 0; mi < 4; ++mi)
        #pragma unroll
        for (int g = 0; g < 3; ++g)
            #pragma unroll
            for (int ni = 0; ni < 2; ++ni)
                acc[mi][g][ni] = (f32x4){0.f, 0.f, 0.f, 0.f};

    for (int k0 = 0; k0 < SH; k0 += 32) {
        // A: chunk (c=sc_, row=sr_) <- h16[m0+sr_][k0+sc_*8 ..]; dest linear
        gl_lds16(h16 + (size_t)(m0 + sr_) * SH + k0 + sc_ * 8, &As[tid * 8]);
        // B: chunk (g=p, c=sc_, col=sr_); dest linear (idx = p*512 + tid)
        #pragma unroll
        for (int p = 0; p < 3; ++p) {
            gl_lds16(W16 + (size_t)(p * SH + c0 + sr_) * SH + k0 + sc_ * 8,
                     &Bs[(size_t)(tid + p * 512) * 8]);
        }
        __syncthreads();

        f16x8 af[4], bf[3][2];
        #pragma unroll
        for (int mi = 0; mi < 4; ++mi)
            af[mi] = *(const f16x8*)&As[(l4 * 128 + wm + mi * 16 + l15) * 8];
        #pragma unroll
        for (int g = 0; g < 3; ++g)
            #pragma unroll
            for (int ni = 0; ni < 2; ++ni)
                bf[g][ni] = *(const f16x8*)
                    &Bs[(g * 512 + l4 * 128 + wn + ni * 16 + l15) * 8];

        #pragma unroll
        for (int mi = 0; mi < 4; ++mi)
            #pragma unroll
            for (int g = 0; g < 3; ++g)
                #pragma unroll
                for (int ni = 0; ni < 2; ++ni)
                    acc[mi][g][ni] = __builtin_amdgcn_mfma_f32_16x16x32_f16(
                        af[mi], bf[g][ni], acc[mi][g][ni], 0, 0, 0);
        __syncthreads();
    }

    float bhh_[3][2], bih_[3][2], gr_[3][2];
    #pragma unroll
    for (int ni = 0; ni < 2; ++ni) {
        const int col = c0 + wn + ni * 16 + l15;
        #pragma unroll
        for (int g = 0; g < 3; ++g) {
            bhh_[g][ni] = b_hh[col + g * SH];
            bih_[g][ni] = b_ih[col + g * SH];
            gr_[g][ni]  = g_raw[col + g * SH];
        }
    }
    #pragma unroll
    for (int mi = 0; mi < 4; ++mi) {
        #pragma unroll
        for (int jj = 0; jj < 4; ++jj) {
            const int row = m0 + wm + mi * 16 + l4 * 4 + jj;
            const float bt = beta[row];
            #pragma unroll
            for (int ni = 0; ni < 2; ++ni) {
                const int col = c0 + wn + ni * 16 + l15;
                const float hp = (float)h16[(size_t)row * SH + col];
                const float ghr = acc[mi][0][ni][jj] + bhh_[0][ni];
                const float ghz = acc[mi][1][ni][jj] + bhh_[1][ni];
                const float ghn = acc[mi][2][ni][jj] + bhh_[2][ni];
                const float gir = fmaf(bt, gr_[0][ni], bih_[0][ni]);
                const float giz = fmaf(bt, gr_[1][ni], bih_[1][ni]);
                const float gin = fmaf(bt, gr_[2][ni], bih_[2][ni]);
                const float r = sigmoid_fast(gir + ghr);
                const float z = sigmoid_fast(giz + ghz);
                const float n = tanh_fast(fmaf(r, ghn, gin));
                out[1 + (size_t)row * SH + col] = (1.0f - z) * n + z * hp;
            }
        }
    }
}

// ---------------------------------------------------------------------------
extern "C" void kernel_launch(void* const* d_in, const int* in_sizes, int n_in,
                              void* d_out, int out_size, void* d_ws, size_t ws_size,
                              hipStream_t stream) {
    const int*   topic     = (const int*)d_in[0];
    const float* knowledge = (const float*)d_in[1];
    const float* score     = (const float*)d_in[2];
    const float* emb       = (const float*)d_in[3];
    const float* Wih_f     = (const float*)d_in[4];
    const float* Whh_f     = (const float*)d_in[5];
    const float* bih_f     = (const float*)d_in[6];
    const float* bhh_f     = (const float*)d_in[7];
    const float* Wih_b     = (const float*)d_in[8];
    const float* Whh_b     = (const float*)d_in[9];
    const float* bih_b     = (const float*)d_in[10];
    const float* bhh_b     = (const float*)d_in[11];
    const float* Wk        = (const float*)d_in[12];
    const float* bk        = (const float*)d_in[13];
    const float* km        = (const float*)d_in[14];
    const float* h0        = (const float*)d_in[15];
    const float* Ws        = (const float*)d_in[16];
    const float* bs        = (const float*)d_in[17];
    const float* Wih_s     = (const float*)d_in[18];
    const float* Whh_s     = (const float*)d_in[19];
    const float* bih_s     = (const float*)d_in[20];
    const float* bhh_s     = (const float*)d_in[21];

    float* out = (float*)d_out;
    float* ws  = (float*)d_ws;

    // workspace layout (floats)
    float* v     = ws + 0;       // 256
    float* kn    = ws + 256;     // 64
    float* alpha = ws + 320;     // 16384
    float* beta  = ws + 16704;   // 16384
    float* part  = ws + 33088;   // 128*512 = 65536
    float* g_raw = ws + 98624;   // 1536
    float* gi_ws = ws + 100672;  // 2*64*384

    const size_t H16_OFF = 655360;                           // 640 KB
    const size_t W16_OFF = H16_OFF + (size_t)KCNT * SH * 2;  // +16 MB
    _Float16* h16 = (_Float16*)((char*)d_ws + H16_OFF);
    _Float16* W16 = (_Float16*)((char*)d_ws + W16_OFF);

    prep_kernel<<<GRID_PREP, 384, 0, stream>>>(
        h0, h16, Whh_s, W16, topic, emb, Wih_f, bih_f, Wih_b, bih_b, gi_ws,
        Wk, bk, knowledge, kn);
    topic_gru_seq_kernel<<<2, 1024, 0, stream>>>(Whh_f, bhh_f, Whh_b, bhh_b,
                                                 gi_ws, v);
    alpha_kernel<<<KCNT * 64 / 256, 256, 0, stream>>>(km, kn, alpha);
    softmax_kernel<<<1, 1024, 0, stream>>>(alpha, beta);
    hkp_gih_kernel<<<320, 512, 0, stream>>>(beta, h16, part, Wih_s, v, score,
                                            g_raw);
    slot_gru_mfma_kernel<<<SLOT_BLOCKS + 1, 512, 0, stream>>>(
        h16, W16, beta, g_raw, bih_s, bhh_s, part, v, Ws, bs, out);
}